// Round 3
// baseline (740.245 us; speedup 1.0000x reference)
//
#include <hip/hip_runtime.h>
#include <math.h>

#define NPTS  65536
#define NG    64
#define NP    16
#define NLAY  20

typedef float f32x2 __attribute__((ext_vector_type(2)));

__device__ __forceinline__ f32x2 splat(float s) { f32x2 r; r.x = s; r.y = s; return r; }

// ---------------------------------------------------------------------------
// Phase A: POCA. One thread per (polygon g, point-pair t) -> points 2t, 2t+1.
// Both points' state packed as f32x2 so FMA-shaped work lowers to
// v_pk_fma_f32 / v_pk_add_f32 (VOP3P, full-rate dual fp32 on CDNA).
// Simplex projection: bitonic-16 sort (scalar max/min) + tau = max_j v_j.
// ---------------------------------------------------------------------------
__global__ __launch_bounds__(256) void poca_kernel(
    const float4* __restrict__ y4, const float* __restrict__ W,
    const float* __restrict__ step_p, const int* __restrict__ polys,
    float4* __restrict__ pts4)
{
    const int g = blockIdx.y;
    const int t = blockIdx.x * 256 + threadIdx.x;   // point-pair index
    const float step = step_p[0];

    // A_g columns; uniform per block -> scalar regs
    float a0[NP], a1[NP], sa0[NP], sa1[NP];
#pragma unroll
    for (int p = 0; p < NP; ++p) {
        const int idx = polys[g * NP + p];
        a0[p] = W[idx * 2 + 0];
        a1[p] = W[idx * 2 + 1];
        sa0[p] = step * a0[p];
        sa1[p] = step * a1[p];
    }

    const float4 yv = y4[t];               // {yA0,yA1,yB0,yB1}
    const f32x2 y0 = { yv.x, yv.z };
    const f32x2 y1 = { yv.y, yv.w };

    f32x2 xt[NP], xo[NP];
#pragma unroll
    for (int p = 0; p < NP; ++p) { xt[p] = splat(0.f); xo[p] = splat(0.f); }

    for (int layer = 0; layer < NLAY; ++layer) {
        // Q = y - x_tmp @ A  (2 components, both points packed)
        f32x2 q0 = y0, q1 = y1;
#pragma unroll
        for (int p = 0; p < NP; ++p) {
            q0 -= xt[p] * splat(a0[p]);    // contracts to v_pk_fma with neg
            q1 -= xt[p] * splat(a1[p]);
        }
        // x = x_tmp + step * (Q @ A^T)
        f32x2 x[NP], u[NP];
#pragma unroll
        for (int p = 0; p < NP; ++p) {
            x[p] = __builtin_elementwise_fma(q0, splat(sa0[p]),
                   __builtin_elementwise_fma(q1, splat(sa1[p]), xt[p]));
            u[p] = x[p];
        }
        // descending bitonic sort of u[16] (elementwise over the pair)
#pragma unroll
        for (int k = 2; k <= NP; k <<= 1) {
#pragma unroll
            for (int j = k >> 1; j > 0; j >>= 1) {
#pragma unroll
                for (int i = 0; i < NP; ++i) {
                    const int l = i ^ j;
                    if (l > i) {
                        const bool up = ((i & k) == 0);   // compile-time
                        const f32x2 mx = __builtin_elementwise_max(u[i], u[l]);
                        const f32x2 mn = __builtin_elementwise_min(u[i], u[l]);
                        u[i] = up ? mx : mn;
                        u[l] = up ? mn : mx;
                    }
                }
            }
        }
        // tau = max_j (prefix_j - 1)/j   (v_j unimodal, peak at valid k)
        f32x2 cs  = u[0];
        f32x2 tau = cs - splat(1.0f);
#pragma unroll
        for (int j = 1; j < NP; ++j) {
            cs += u[j];
            const float c = 1.0f / (float)(j + 1);
            const f32x2 vj = __builtin_elementwise_fma(cs, splat(c), splat(-c));
            tau = __builtin_elementwise_max(tau, vj);
        }
        // x_new = relu(x - tau); Nesterov
        const float cn = (float)layer / ((float)layer + 3.0f);
#pragma unroll
        for (int p = 0; p < NP; ++p) {
            const f32x2 xn = __builtin_elementwise_max(x[p] - tau, splat(0.f));
            xt[p] = __builtin_elementwise_fma(splat(cn), xn - xo[p], xn);
            xo[p] = xn;
        }
    }

    // points = x_new @ A
    f32x2 p0 = splat(0.f), p1 = splat(0.f);
#pragma unroll
    for (int p = 0; p < NP; ++p) {
        p0 = __builtin_elementwise_fma(xo[p], splat(a0[p]), p0);
        p1 = __builtin_elementwise_fma(xo[p], splat(a1[p]), p1);
    }
    pts4[(size_t)g * (NPTS / 2) + t] = make_float4(p0.x, p1.x, p0.y, p1.y);
}

// ---------------------------------------------------------------------------
// Phase B: f-iteration over 65-element rows + fused yhat/f/f0 epilogue.
// (unchanged from the passing round-2 version; ~40 us)
// ---------------------------------------------------------------------------
__global__ __launch_bounds__(256) void fiter_kernel(
    const float* __restrict__ y, const float* __restrict__ step_p,
    const float2* __restrict__ pts, float* __restrict__ out)
{
    const int n = blockIdx.x * 256 + threadIdx.x;
    const float step = step_p[0];
    const float y0 = y[2 * n + 0];
    const float y1 = y[2 * n + 1];

    float gs[NG + 1];
    gs[0] = step;
#pragma unroll
    for (int g = 0; g < NG; ++g) {
        const float2 p = pts[(size_t)g * NPTS + n];
        const float dx = y0 - p.x;
        const float dy = y1 - p.y;
        gs[1 + g] = sqrtf(dx * dx + dy * dy) * step;
    }

    float x[NG + 1], fo[NG + 1];
#pragma unroll
    for (int i = 0; i <= NG; ++i) { x[i] = 0.f; fo[i] = 0.f; }

    for (int layer = 0; layer < NLAY; ++layer) {
        float s0 = 0.f, s1 = 0.f, s2 = 0.f, s3 = 0.f;
#pragma unroll
        for (int i = 0; i <= NG; ++i) {
            x[i] -= gs[i];
            if ((i & 3) == 0)      s0 += x[i];
            else if ((i & 3) == 1) s1 += x[i];
            else if ((i & 3) == 2) s2 += x[i];
            else                   s3 += x[i];
        }
        float tau = ((s0 + s1) + (s2 + s3) - 1.0f) * (1.0f / 65.0f);
        int kprev = NG + 1;
        for (int pass = 0; pass < NG + 1; ++pass) {
            float t0 = 0.f, t1 = 0.f, t2 = 0.f, t3 = 0.f;
            int cnt = 0;
#pragma unroll
            for (int i = 0; i <= NG; ++i) {
                const bool in = x[i] > tau;
                const float xv = in ? x[i] : 0.f;
                if ((i & 3) == 0)      t0 += xv;
                else if ((i & 3) == 1) t1 += xv;
                else if ((i & 3) == 2) t2 += xv;
                else                   t3 += xv;
                cnt += in ? 1 : 0;
            }
            if (cnt == kprev) break;
            kprev = cnt;
            tau = (((t0 + t1) + (t2 + t3)) - 1.0f) / (float)cnt;
        }
        const float c = (float)layer / ((float)layer + 3.0f);
#pragma unroll
        for (int i = 0; i <= NG; ++i) {
            const float fn = fmaxf(x[i] - tau, 0.f);
            x[i] = fmaf(c, fn - fo[i], fn);
            fo[i] = fn;
        }
    }

    float acc0 = y0 * fo[0];
    float acc1 = y1 * fo[0];
#pragma unroll
    for (int g = 0; g < NG; ++g) {
        const float2 p = pts[(size_t)g * NPTS + n];
        acc0 = fmaf(fo[1 + g], p.x, acc0);
        acc1 = fmaf(fo[1 + g], p.y, acc1);
    }

    ((float2*)out)[n] = make_float2(acc0, acc1);
    float4* fsec = (float4*)(out + 2 * (size_t)NPTS);
#pragma unroll
    for (int g4 = 0; g4 < NG / 4; ++g4) {
        fsec[(size_t)n * (NG / 4) + g4] = make_float4(
            fo[1 + 4 * g4], fo[2 + 4 * g4], fo[3 + 4 * g4], fo[4 + 4 * g4]);
    }
    out[2 * (size_t)NPTS + (size_t)NPTS * NG + n] = fo[0];
}

// ---------------------------------------------------------------------------
extern "C" void kernel_launch(void* const* d_in, const int* in_sizes, int n_in,
                              void* d_out, int out_size, void* d_ws, size_t ws_size,
                              hipStream_t stream) {
    const float*  y     = (const float*)d_in[0];
    const float4* y4    = (const float4*)d_in[0];
    const float*  W     = (const float*)d_in[1];
    const float*  step  = (const float*)d_in[2];
    const int*    polys = (const int*)d_in[3];
    float*        out   = (float*)d_out;
    float4*       pts4  = (float4*)d_ws;     // 64*32768*16B = 32 MB
    const float2* pts2  = (const float2*)d_ws;

    dim3 gridA(NPTS / 2 / 256, NG);
    poca_kernel<<<gridA, 256, 0, stream>>>(y4, W, step, polys, pts4);
    fiter_kernel<<<NPTS / 256, 256, 0, stream>>>(y, step, pts2, out);
}

// Round 5
// 731.665 us; speedup vs baseline: 1.0117x; 1.0117x over previous
//
#include <hip/hip_runtime.h>
#include <math.h>

#define NPTS  65536
#define NG    64
#define NP    16
#define NLAY  20

// ---------------------------------------------------------------------------
// Batcher odd-even mergesort network for 16 inputs (63 comparators),
// generated at compile time from the canonical formula (no hand transcription).
// ---------------------------------------------------------------------------
struct Net { int a[63]; int b[63]; int cnt; };
constexpr Net make_batcher16() {
    Net net{};
    int c = 0;
    const int n = 16;
    for (int p = 1; p < n; p <<= 1)
        for (int k = p; k >= 1; k >>= 1)
            for (int j = k % p; j + k < n; j += 2 * k)
                for (int i = 0; i < k && i + j + k < n; ++i)
                    if ((i + j) / (2 * p) == (i + j + k) / (2 * p)) {
                        net.a[c] = i + j;
                        net.b[c] = i + j + k;
                        ++c;
                    }
    net.cnt = c;
    return net;
}
constexpr Net BNET = make_batcher16();
static_assert(BNET.cnt == 63, "Batcher-16 must have exactly 63 comparators");

// ---------------------------------------------------------------------------
// Phase A: POCA. One thread per (polygon g, point n). All state fp32 (f16
// failed: dynamics amplify eps by ~1e5). sqrt(step) folded into A and y:
//   x = xt + (y' - xt@A')@A'^T  ==  xt + step*(y - xt@A)@A^T   (exact math)
// Simplex projection: Batcher-63 descending sort (flipped comparators) +
// tau = max_j (prefix_j - 1)/j (unimodal-peak identity, validated round 3).
// ---------------------------------------------------------------------------
__global__ __launch_bounds__(256) void poca_kernel(
    const float2* __restrict__ y2, const float* __restrict__ W,
    const float* __restrict__ step_p, const int* __restrict__ polys,
    float2* __restrict__ pts)
{
    const int g = blockIdx.y;
    const int n = blockIdx.x * 256 + threadIdx.x;
    const float step = step_p[0];
    const float rs = sqrtf(step);
    const float inv_rs = 1.0f / rs;

    // A' = rs*A columns (uniform per block -> L1-hot broadcast loads)
    float a0[NP], a1[NP];
#pragma unroll
    for (int p = 0; p < NP; ++p) {
        const int idx = polys[g * NP + p];
        a0[p] = rs * W[idx * 2 + 0];
        a1[p] = rs * W[idx * 2 + 1];
    }

    const float2 yv = y2[n];
    const float y0 = rs * yv.x;
    const float y1 = rs * yv.y;

    float xt[NP], xo[NP];
#pragma unroll
    for (int p = 0; p < NP; ++p) { xt[p] = 0.f; xo[p] = 0.f; }

    for (int layer = 0; layer < NLAY; ++layer) {
        // q' = y' - xt@A'
        float q0 = y0, q1 = y1;
#pragma unroll
        for (int p = 0; p < NP; ++p) {
            q0 = fmaf(-xt[p], a0[p], q0);
            q1 = fmaf(-xt[p], a1[p], q1);
        }
        // x = xt + q'@A'^T  (== xt + step*(Q@A^T)), 2 fma per p
        float x[NP], u[NP];
#pragma unroll
        for (int p = 0; p < NP; ++p) {
            x[p] = fmaf(q0, a0[p], fmaf(q1, a1[p], xt[p]));
            u[p] = x[p];                      // SSA copy-propagated into CE stage 1
        }
        // descending Batcher sort: 63 flipped comparators (max at low index)
#pragma unroll
        for (int c = 0; c < 63; ++c) {
            const int ia = BNET.a[c], ib = BNET.b[c];   // constants after unroll
            const float mx = fmaxf(u[ia], u[ib]);
            const float mn = fminf(u[ia], u[ib]);
            u[ia] = mx; u[ib] = mn;
        }
        // tau = max_j (prefix_j - 1)/j   (peak at the valid active count)
        float cs  = u[0];
        float tau = cs - 1.0f;
#pragma unroll
        for (int j = 1; j < NP; ++j) {
            cs += u[j];
            const float r = 1.0f / (float)(j + 1);
            tau = fmaxf(tau, fmaf(cs, r, -r));
        }
        // x_new = relu(x - tau); Nesterov momentum
        const float cn = (float)layer / ((float)layer + 3.0f);
#pragma unroll
        for (int p = 0; p < NP; ++p) {
            const float xn = fmaxf(x[p] - tau, 0.f);
            xt[p] = fmaf(cn, xn - xo[p], xn);
            xo[p] = xn;
        }
    }

    // points = x_new @ A = (x_new @ A') / rs
    float p0 = 0.f, p1 = 0.f;
#pragma unroll
    for (int p = 0; p < NP; ++p) {
        p0 = fmaf(xo[p], a0[p], p0);
        p1 = fmaf(xo[p], a1[p], p1);
    }
    pts[(size_t)g * NPTS + n] = make_float2(p0 * inv_rs, p1 * inv_rs);
}

// ---------------------------------------------------------------------------
// Phase B: f-iteration over 65-element rows + fused yhat/f/f0 epilogue.
// (unchanged, validated rounds 2-3; ~40 us)
// ---------------------------------------------------------------------------
__global__ __launch_bounds__(256) void fiter_kernel(
    const float* __restrict__ y, const float* __restrict__ step_p,
    const float2* __restrict__ pts, float* __restrict__ out)
{
    const int n = blockIdx.x * 256 + threadIdx.x;
    const float step = step_p[0];
    const float y0 = y[2 * n + 0];
    const float y1 = y[2 * n + 1];

    float gs[NG + 1];
    gs[0] = step;
#pragma unroll
    for (int g = 0; g < NG; ++g) {
        const float2 p = pts[(size_t)g * NPTS + n];
        const float dx = y0 - p.x;
        const float dy = y1 - p.y;
        gs[1 + g] = sqrtf(dx * dx + dy * dy) * step;
    }

    float x[NG + 1], fo[NG + 1];
#pragma unroll
    for (int i = 0; i <= NG; ++i) { x[i] = 0.f; fo[i] = 0.f; }

    for (int layer = 0; layer < NLAY; ++layer) {
        float s0 = 0.f, s1 = 0.f, s2 = 0.f, s3 = 0.f;
#pragma unroll
        for (int i = 0; i <= NG; ++i) {
            x[i] -= gs[i];
            if ((i & 3) == 0)      s0 += x[i];
            else if ((i & 3) == 1) s1 += x[i];
            else if ((i & 3) == 2) s2 += x[i];
            else                   s3 += x[i];
        }
        float tau = ((s0 + s1) + (s2 + s3) - 1.0f) * (1.0f / 65.0f);
        int kprev = NG + 1;
        for (int pass = 0; pass < NG + 1; ++pass) {
            float t0 = 0.f, t1 = 0.f, t2 = 0.f, t3 = 0.f;
            int cnt = 0;
#pragma unroll
            for (int i = 0; i <= NG; ++i) {
                const bool in = x[i] > tau;
                const float xv = in ? x[i] : 0.f;
                if ((i & 3) == 0)      t0 += xv;
                else if ((i & 3) == 1) t1 += xv;
                else if ((i & 3) == 2) t2 += xv;
                else                   t3 += xv;
                cnt += in ? 1 : 0;
            }
            if (cnt == kprev) break;
            kprev = cnt;
            tau = (((t0 + t1) + (t2 + t3)) - 1.0f) / (float)cnt;
        }
        const float c = (float)layer / ((float)layer + 3.0f);
#pragma unroll
        for (int i = 0; i <= NG; ++i) {
            const float fn = fmaxf(x[i] - tau, 0.f);
            x[i] = fmaf(c, fn - fo[i], fn);
            fo[i] = fn;
        }
    }

    float acc0 = y0 * fo[0];
    float acc1 = y1 * fo[0];
#pragma unroll
    for (int g = 0; g < NG; ++g) {
        const float2 p = pts[(size_t)g * NPTS + n];
        acc0 = fmaf(fo[1 + g], p.x, acc0);
        acc1 = fmaf(fo[1 + g], p.y, acc1);
    }

    ((float2*)out)[n] = make_float2(acc0, acc1);
    float4* fsec = (float4*)(out + 2 * (size_t)NPTS);
#pragma unroll
    for (int g4 = 0; g4 < NG / 4; ++g4) {
        fsec[(size_t)n * (NG / 4) + g4] = make_float4(
            fo[1 + 4 * g4], fo[2 + 4 * g4], fo[3 + 4 * g4], fo[4 + 4 * g4]);
    }
    out[2 * (size_t)NPTS + (size_t)NPTS * NG + n] = fo[0];
}

// ---------------------------------------------------------------------------
extern "C" void kernel_launch(void* const* d_in, const int* in_sizes, int n_in,
                              void* d_out, int out_size, void* d_ws, size_t ws_size,
                              hipStream_t stream) {
    const float*  y     = (const float*)d_in[0];
    const float2* y2    = (const float2*)d_in[0];
    const float*  W     = (const float*)d_in[1];
    const float*  step  = (const float*)d_in[2];
    const int*    polys = (const int*)d_in[3];
    float*        out   = (float*)d_out;
    float2*       pts   = (float2*)d_ws;     // 64*65536*8B = 32 MB

    dim3 gridA(NPTS / 256, NG);
    poca_kernel<<<gridA, 256, 0, stream>>>(y2, W, step, polys, pts);
    fiter_kernel<<<NPTS / 256, 256, 0, stream>>>(y, step, pts, out);
}

// Round 6
// 677.409 us; speedup vs baseline: 1.0928x; 1.0801x over previous
//
#include <hip/hip_runtime.h>
#include <math.h>

#define NPTS  65536
#define NG    64
#define NP    16
#define NLAY  20

// ---------------------------------------------------------------------------
// Batcher odd-even mergesort network for 16 inputs (63 comparators),
// generated at compile time from the canonical formula.
// First 8 comparators are the disjoint pairs (0,1)(2,3)...(14,15) — verified
// by static_assert below — so sort stage 1 can read x[] directly (no copy).
// ---------------------------------------------------------------------------
struct Net { int a[63]; int b[63]; int cnt; };
constexpr Net make_batcher16() {
    Net net{};
    int c = 0;
    const int n = 16;
    for (int p = 1; p < n; p <<= 1)
        for (int k = p; k >= 1; k >>= 1)
            for (int j = k % p; j + k < n; j += 2 * k)
                for (int i = 0; i < k && i + j + k < n; ++i)
                    if ((i + j) / (2 * p) == (i + j + k) / (2 * p)) {
                        net.a[c] = i + j;
                        net.b[c] = i + j + k;
                        ++c;
                    }
    net.cnt = c;
    return net;
}
constexpr Net BNET = make_batcher16();
static_assert(BNET.cnt == 63, "Batcher-16 must have exactly 63 comparators");
constexpr bool stage1_is_disjoint_pairs() {
    for (int c = 0; c < 8; ++c)
        if (BNET.a[c] != 2 * c || BNET.b[c] != 2 * c + 1) return false;
    return true;
}
static_assert(stage1_is_disjoint_pairs(), "stage-1 copy-absorption invalid");

// Simplex projection: descending Batcher sort + tau = max_j (prefix_j - 1)/j.
// Reads x[], clobbers u[], returns tau. Bit-exact vs round-5 version.
__device__ __forceinline__ float simplex_tau(const float* __restrict__ x,
                                             float* __restrict__ u) {
#pragma unroll
    for (int c = 0; c < 8; ++c) {          // stage 1: read x directly
        const int ia = BNET.a[c], ib = BNET.b[c];
        u[ia] = fmaxf(x[ia], x[ib]);
        u[ib] = fminf(x[ia], x[ib]);
    }
#pragma unroll
    for (int c = 8; c < 63; ++c) {
        const int ia = BNET.a[c], ib = BNET.b[c];
        const float mx = fmaxf(u[ia], u[ib]);
        const float mn = fminf(u[ia], u[ib]);
        u[ia] = mx; u[ib] = mn;
    }
    // v_j = (prefix_j - 1)/j for j=1..16 (v_1 = u0-1); reduce via max3 triples
    float vv[NP];
    float cs = u[0];
    vv[0] = cs - 1.0f;
#pragma unroll
    for (int j = 1; j < NP; ++j) {
        cs += u[j];
        const float r = 1.0f / (float)(j + 1);
        vv[j] = fmaf(cs, r, -r);
    }
    // 16 -> 6 -> 2 -> 1 (max is associative: order-exact)
    float m0 = fmaxf(fmaxf(vv[0], vv[1]), vv[2]);
    float m1 = fmaxf(fmaxf(vv[3], vv[4]), vv[5]);
    float m2 = fmaxf(fmaxf(vv[6], vv[7]), vv[8]);
    float m3 = fmaxf(fmaxf(vv[9], vv[10]), vv[11]);
    float m4 = fmaxf(fmaxf(vv[12], vv[13]), vv[14]);
    float m5 = vv[15];
    float n0 = fmaxf(fmaxf(m0, m1), m2);
    float n1 = fmaxf(fmaxf(m3, m4), m5);
    return fmaxf(n0, n1);
}

// ---------------------------------------------------------------------------
// Phase A: POCA. One thread per (polygon g, point n). State fp32 (f16 failed:
// dynamics amplify eps ~1e5x). sqrt(step) folded: A' = rs*A, y' = rs*y makes
//   x = xt + (y' - xt@A')@A'^T == xt + step*(y - xt@A)@A^T  (exact math).
// Layer 0 peeled (xt=xo=0, Nesterov coeff = 0): bit-identical arithmetic.
// ---------------------------------------------------------------------------
__global__ __launch_bounds__(256) void poca_kernel(
    const float2* __restrict__ y2, const float* __restrict__ W,
    const float* __restrict__ step_p, const int* __restrict__ polys,
    float2* __restrict__ pts)
{
    const int g = blockIdx.y;
    const int n = blockIdx.x * 256 + threadIdx.x;
    const float step = step_p[0];
    const float rs = sqrtf(step);
    const float inv_rs = 1.0f / rs;

    float a0[NP], a1[NP];
#pragma unroll
    for (int p = 0; p < NP; ++p) {
        const int idx = polys[g * NP + p];
        a0[p] = rs * W[idx * 2 + 0];
        a1[p] = rs * W[idx * 2 + 1];
    }

    const float2 yv = y2[n];
    const float y0 = rs * yv.x;
    const float y1 = rs * yv.y;

    float xt[NP], xo[NP], x[NP], u[NP];

    // ---- layer 0 (peeled): xt=xo=0, q=y', coeff=0 -> xt=xo=xn ----
#pragma unroll
    for (int p = 0; p < NP; ++p)
        x[p] = fmaf(y0, a0[p], y1 * a1[p]);
    {
        const float tau = simplex_tau(x, u);
#pragma unroll
        for (int p = 0; p < NP; ++p) {
            const float xn = fmaxf(x[p] - tau, 0.f);
            xt[p] = xn; xo[p] = xn;
        }
    }

    // ---- layers 1..19 ----
    for (int layer = 1; layer < NLAY; ++layer) {
        float q0 = y0, q1 = y1;
#pragma unroll
        for (int p = 0; p < NP; ++p) {
            q0 = fmaf(-xt[p], a0[p], q0);
            q1 = fmaf(-xt[p], a1[p], q1);
        }
#pragma unroll
        for (int p = 0; p < NP; ++p)
            x[p] = fmaf(q0, a0[p], fmaf(q1, a1[p], xt[p]));

        const float tau = simplex_tau(x, u);

        const float cn = (float)layer / ((float)layer + 3.0f);
#pragma unroll
        for (int p = 0; p < NP; ++p) {
            const float xn = fmaxf(x[p] - tau, 0.f);
            xt[p] = fmaf(cn, xn - xo[p], xn);
            xo[p] = xn;
        }
    }

    // points = x_new @ A = (x_new @ A') / rs
    float p0 = 0.f, p1 = 0.f;
#pragma unroll
    for (int p = 0; p < NP; ++p) {
        p0 = fmaf(xo[p], a0[p], p0);
        p1 = fmaf(xo[p], a1[p], p1);
    }
    pts[(size_t)g * NPTS + n] = make_float2(p0 * inv_rs, p1 * inv_rs);
}

// ---------------------------------------------------------------------------
// Phase B: f-iteration over 65-element rows + fused yhat/f/f0 epilogue.
// (unchanged, validated rounds 2-5; ~40 us)
// ---------------------------------------------------------------------------
__global__ __launch_bounds__(256) void fiter_kernel(
    const float* __restrict__ y, const float* __restrict__ step_p,
    const float2* __restrict__ pts, float* __restrict__ out)
{
    const int n = blockIdx.x * 256 + threadIdx.x;
    const float step = step_p[0];
    const float y0 = y[2 * n + 0];
    const float y1 = y[2 * n + 1];

    float gs[NG + 1];
    gs[0] = step;
#pragma unroll
    for (int g = 0; g < NG; ++g) {
        const float2 p = pts[(size_t)g * NPTS + n];
        const float dx = y0 - p.x;
        const float dy = y1 - p.y;
        gs[1 + g] = sqrtf(dx * dx + dy * dy) * step;
    }

    float x[NG + 1], fo[NG + 1];
#pragma unroll
    for (int i = 0; i <= NG; ++i) { x[i] = 0.f; fo[i] = 0.f; }

    for (int layer = 0; layer < NLAY; ++layer) {
        float s0 = 0.f, s1 = 0.f, s2 = 0.f, s3 = 0.f;
#pragma unroll
        for (int i = 0; i <= NG; ++i) {
            x[i] -= gs[i];
            if ((i & 3) == 0)      s0 += x[i];
            else if ((i & 3) == 1) s1 += x[i];
            else if ((i & 3) == 2) s2 += x[i];
            else                   s3 += x[i];
        }
        float tau = ((s0 + s1) + (s2 + s3) - 1.0f) * (1.0f / 65.0f);
        int kprev = NG + 1;
        for (int pass = 0; pass < NG + 1; ++pass) {
            float t0 = 0.f, t1 = 0.f, t2 = 0.f, t3 = 0.f;
            int cnt = 0;
#pragma unroll
            for (int i = 0; i <= NG; ++i) {
                const bool in = x[i] > tau;
                const float xv = in ? x[i] : 0.f;
                if ((i & 3) == 0)      t0 += xv;
                else if ((i & 3) == 1) t1 += xv;
                else if ((i & 3) == 2) t2 += xv;
                else                   t3 += xv;
                cnt += in ? 1 : 0;
            }
            if (cnt == kprev) break;
            kprev = cnt;
            tau = (((t0 + t1) + (t2 + t3)) - 1.0f) / (float)cnt;
        }
        const float c = (float)layer / ((float)layer + 3.0f);
#pragma unroll
        for (int i = 0; i <= NG; ++i) {
            const float fn = fmaxf(x[i] - tau, 0.f);
            x[i] = fmaf(c, fn - fo[i], fn);
            fo[i] = fn;
        }
    }

    float acc0 = y0 * fo[0];
    float acc1 = y1 * fo[0];
#pragma unroll
    for (int g = 0; g < NG; ++g) {
        const float2 p = pts[(size_t)g * NPTS + n];
        acc0 = fmaf(fo[1 + g], p.x, acc0);
        acc1 = fmaf(fo[1 + g], p.y, acc1);
    }

    ((float2*)out)[n] = make_float2(acc0, acc1);
    float4* fsec = (float4*)(out + 2 * (size_t)NPTS);
#pragma unroll
    for (int g4 = 0; g4 < NG / 4; ++g4) {
        fsec[(size_t)n * (NG / 4) + g4] = make_float4(
            fo[1 + 4 * g4], fo[2 + 4 * g4], fo[3 + 4 * g4], fo[4 + 4 * g4]);
    }
    out[2 * (size_t)NPTS + (size_t)NPTS * NG + n] = fo[0];
}

// ---------------------------------------------------------------------------
extern "C" void kernel_launch(void* const* d_in, const int* in_sizes, int n_in,
                              void* d_out, int out_size, void* d_ws, size_t ws_size,
                              hipStream_t stream) {
    const float*  y     = (const float*)d_in[0];
    const float2* y2    = (const float2*)d_in[0];
    const float*  W     = (const float*)d_in[1];
    const float*  step  = (const float*)d_in[2];
    const int*    polys = (const int*)d_in[3];
    float*        out   = (float*)d_out;
    float2*       pts   = (float2*)d_ws;     // 64*65536*8B = 32 MB

    dim3 gridA(NPTS / 256, NG);
    poca_kernel<<<gridA, 256, 0, stream>>>(y2, W, step, polys, pts);
    fiter_kernel<<<NPTS / 256, 256, 0, stream>>>(y, step, pts, out);
}

// Round 7
// 638.040 us; speedup vs baseline: 1.1602x; 1.0617x over previous
//
#include <hip/hip_runtime.h>
#include <math.h>

#define NPTS  65536
#define NG    64
#define NP    16
#define NLAY  20

// ---------------------------------------------------------------------------
// Batcher odd-even mergesort network for 16 inputs (63 comparators),
// generated at compile time from the canonical formula.
// ---------------------------------------------------------------------------
struct Net { int a[63]; int b[63]; int cnt; };
constexpr Net make_batcher16() {
    Net net{};
    int c = 0;
    const int n = 16;
    for (int p = 1; p < n; p <<= 1)
        for (int k = p; k >= 1; k >>= 1)
            for (int j = k % p; j + k < n; j += 2 * k)
                for (int i = 0; i < k && i + j + k < n; ++i)
                    if ((i + j) / (2 * p) == (i + j + k) / (2 * p)) {
                        net.a[c] = i + j;
                        net.b[c] = i + j + k;
                        ++c;
                    }
    net.cnt = c;
    return net;
}
constexpr Net BNET = make_batcher16();
static_assert(BNET.cnt == 63, "Batcher-16 must have exactly 63 comparators");
constexpr bool stage1_is_disjoint_pairs() {
    for (int c = 0; c < 8; ++c)
        if (BNET.a[c] != 2 * c || BNET.b[c] != 2 * c + 1) return false;
    return true;
}
static_assert(stage1_is_disjoint_pairs(), "stage-1 copy-absorption invalid");

// Simplex projection: descending Batcher sort + tau = max_j (prefix_j - 1)/j.
__device__ __forceinline__ float simplex_tau(const float* __restrict__ x,
                                             float* __restrict__ u) {
#pragma unroll
    for (int c = 0; c < 8; ++c) {          // stage 1: read x directly
        const int ia = BNET.a[c], ib = BNET.b[c];
        u[ia] = fmaxf(x[ia], x[ib]);
        u[ib] = fminf(x[ia], x[ib]);
    }
#pragma unroll
    for (int c = 8; c < 63; ++c) {
        const int ia = BNET.a[c], ib = BNET.b[c];
        const float mx = fmaxf(u[ia], u[ib]);
        const float mn = fminf(u[ia], u[ib]);
        u[ia] = mx; u[ib] = mn;
    }
    float vv[NP];
    float cs = u[0];
    vv[0] = cs - 1.0f;
#pragma unroll
    for (int j = 1; j < NP; ++j) {
        cs += u[j];
        const float r = 1.0f / (float)(j + 1);
        vv[j] = fmaf(cs, r, -r);
    }
    float m0 = fmaxf(fmaxf(vv[0], vv[1]), vv[2]);
    float m1 = fmaxf(fmaxf(vv[3], vv[4]), vv[5]);
    float m2 = fmaxf(fmaxf(vv[6], vv[7]), vv[8]);
    float m3 = fmaxf(fmaxf(vv[9], vv[10]), vv[11]);
    float m4 = fmaxf(fmaxf(vv[12], vv[13]), vv[14]);
    float m5 = vv[15];
    float n0 = fmaxf(fmaxf(m0, m1), m2);
    float n1 = fmaxf(fmaxf(m3, m4), m5);
    return fmaxf(n0, n1);
}

// ---------------------------------------------------------------------------
// Phase A: POCA (unchanged from validated round 6; VALU-issue-bound).
// ---------------------------------------------------------------------------
__global__ __launch_bounds__(256) void poca_kernel(
    const float2* __restrict__ y2, const float* __restrict__ W,
    const float* __restrict__ step_p, const int* __restrict__ polys,
    float2* __restrict__ pts)
{
    const int g = blockIdx.y;
    const int n = blockIdx.x * 256 + threadIdx.x;
    const float step = step_p[0];
    const float rs = sqrtf(step);
    const float inv_rs = 1.0f / rs;

    float a0[NP], a1[NP];
#pragma unroll
    for (int p = 0; p < NP; ++p) {
        const int idx = polys[g * NP + p];
        a0[p] = rs * W[idx * 2 + 0];
        a1[p] = rs * W[idx * 2 + 1];
    }

    const float2 yv = y2[n];
    const float y0 = rs * yv.x;
    const float y1 = rs * yv.y;

    float xt[NP], xo[NP], x[NP], u[NP];

    // layer 0 (peeled): xt=xo=0, q=y', Nesterov coeff = 0
#pragma unroll
    for (int p = 0; p < NP; ++p)
        x[p] = fmaf(y0, a0[p], y1 * a1[p]);
    {
        const float tau = simplex_tau(x, u);
#pragma unroll
        for (int p = 0; p < NP; ++p) {
            const float xn = fmaxf(x[p] - tau, 0.f);
            xt[p] = xn; xo[p] = xn;
        }
    }

    for (int layer = 1; layer < NLAY; ++layer) {
        float q0 = y0, q1 = y1;
#pragma unroll
        for (int p = 0; p < NP; ++p) {
            q0 = fmaf(-xt[p], a0[p], q0);
            q1 = fmaf(-xt[p], a1[p], q1);
        }
#pragma unroll
        for (int p = 0; p < NP; ++p)
            x[p] = fmaf(q0, a0[p], fmaf(q1, a1[p], xt[p]));

        const float tau = simplex_tau(x, u);

        const float cn = (float)layer / ((float)layer + 3.0f);
#pragma unroll
        for (int p = 0; p < NP; ++p) {
            const float xn = fmaxf(x[p] - tau, 0.f);
            xt[p] = fmaf(cn, xn - xo[p], xn);
            xo[p] = xn;
        }
    }

    float p0 = 0.f, p1 = 0.f;
#pragma unroll
    for (int p = 0; p < NP; ++p) {
        p0 = fmaf(xo[p], a0[p], p0);
        p1 = fmaf(xo[p], a1[p], p1);
    }
    pts[(size_t)g * NPTS + n] = make_float2(p0 * inv_rs, p1 * inv_rs);
}

// ---------------------------------------------------------------------------
// Phase B: f-iteration, 4-lane split. Lanes 4t..4t+3 share point n; lane
// slice s owns g in [16s, 16s+16); slice 0 also owns the f0 element.
// Michelot active-set fixpoint with cross-lane butterfly reductions
// (__shfl_xor masks 1,2 -> DPP quad-perm, stays in-group). Dummy f0 element
// on slices 1..3 is pinned to -1e30 so it never enters sums or counts.
// Occupancy: 4096 waves (4/SIMD) vs 1024 (1/SIMD) for the 1-lane version.
// ---------------------------------------------------------------------------
__global__ __launch_bounds__(256) void fiter_kernel(
    const float2* __restrict__ y2, const float* __restrict__ step_p,
    const float2* __restrict__ pts, float* __restrict__ out)
{
    const int gt = blockIdx.x * 256 + threadIdx.x;
    const int n  = gt >> 2;          // point index
    const int s  = gt & 3;           // slice
    const bool lead = (s == 0);
    const float NEG = -1e30f;
    const float step = step_p[0];
    const float2 yv = y2[n];
    const float y0 = yv.x, y1 = yv.y;

    // gs for owned slice: g = 16*s + j
    float gs[16];
#pragma unroll
    for (int j = 0; j < 16; ++j) {
        const float2 p = pts[(size_t)(16 * s + j) * NPTS + n];
        const float dx = y0 - p.x;
        const float dy = y1 - p.y;
        gs[j] = sqrtf(dx * dx + dy * dy) * step;
    }
    const float gs0 = lead ? step : 0.f;
    const float msk0 = lead ? 1.f : 0.f;

    float x[16], fo[16];
#pragma unroll
    for (int j = 0; j < 16; ++j) { x[j] = 0.f; fo[j] = 0.f; }
    float x0 = lead ? 0.f : NEG;
    float fo0 = 0.f;

    for (int layer = 0; layer < NLAY; ++layer) {
        // x -= gs; full-sum seed
        float t0 = 0.f, t1 = 0.f, t2 = 0.f, t3 = 0.f;
#pragma unroll
        for (int j = 0; j < 16; ++j) {
            x[j] -= gs[j];
            if ((j & 3) == 0)      t0 += x[j];
            else if ((j & 3) == 1) t1 += x[j];
            else if ((j & 3) == 2) t2 += x[j];
            else                   t3 += x[j];
        }
        x0 -= gs0;                         // NEG stays NEG on non-lead
        float t = (t0 + t1) + (t2 + t3);
        t = fmaf(msk0, x0, t);             // include f0 elem on lead only
        t += __shfl_xor(t, 1);
        t += __shfl_xor(t, 2);
        float tau = (t - 1.0f) * (1.0f / 65.0f);

        float kprev = 65.f;
        for (int pass = 0; pass < NG + 1; ++pass) {
            float a0 = 0.f, a1 = 0.f, a2 = 0.f, a3 = 0.f;
            float c0 = 0.f, c1 = 0.f, c2 = 0.f, c3 = 0.f;
#pragma unroll
            for (int j = 0; j < 16; ++j) {
                const float f = (x[j] > tau) ? 1.f : 0.f;
                if ((j & 3) == 0)      { a0 = fmaf(f, x[j], a0); c0 += f; }
                else if ((j & 3) == 1) { a1 = fmaf(f, x[j], a1); c1 += f; }
                else if ((j & 3) == 2) { a2 = fmaf(f, x[j], a2); c2 += f; }
                else                   { a3 = fmaf(f, x[j], a3); c3 += f; }
            }
            const float f0 = (x0 > tau) ? 1.f : 0.f;   // never on dummies
            float aa = (a0 + a1) + (a2 + a3);
            aa = fmaf(f0, x0, aa);
            float cc = ((c0 + c1) + (c2 + c3)) + f0;
            aa += __shfl_xor(aa, 1);
            aa += __shfl_xor(aa, 2);
            cc += __shfl_xor(cc, 1);
            cc += __shfl_xor(cc, 2);
            if (cc == kprev) break;        // group-uniform (reduced values)
            kprev = cc;
            tau = (aa - 1.0f) / cc;
        }

        const float c = (float)layer / ((float)layer + 3.0f);
#pragma unroll
        for (int j = 0; j < 16; ++j) {
            const float fn = fmaxf(x[j] - tau, 0.f);
            x[j] = fmaf(c, fn - fo[j], fn);
            fo[j] = fn;
        }
        const float fn0 = fmaxf(x0 - tau, 0.f);        // 0 on dummies
        const float xt0 = fmaf(c, fn0 - fo0, fn0);
        fo0 = fn0;
        x0 = lead ? xt0 : NEG;             // re-pin dummy
    }

    // epilogue: partial einsum + cross-lane reduce
    float acc0 = 0.f, acc1 = 0.f;
#pragma unroll
    for (int j = 0; j < 16; ++j) {
        const float2 p = pts[(size_t)(16 * s + j) * NPTS + n];
        acc0 = fmaf(fo[j], p.x, acc0);
        acc1 = fmaf(fo[j], p.y, acc1);
    }
    acc0 += __shfl_xor(acc0, 1);
    acc0 += __shfl_xor(acc0, 2);
    acc1 += __shfl_xor(acc1, 1);
    acc1 += __shfl_xor(acc1, 2);

    // f slice: out[2N + n*64 + 16s + j] -> 4 float4 stores
    float4* fsec = (float4*)(out + 2 * (size_t)NPTS);
#pragma unroll
    for (int q = 0; q < 4; ++q) {
        fsec[(size_t)n * 16 + 4 * s + q] = make_float4(
            fo[4 * q + 0], fo[4 * q + 1], fo[4 * q + 2], fo[4 * q + 3]);
    }

    if (lead) {
        ((float2*)out)[n] = make_float2(fmaf(y0, fo0, acc0),
                                        fmaf(y1, fo0, acc1));
        out[2 * (size_t)NPTS + (size_t)NPTS * NG + n] = fo0;
    }
}

// ---------------------------------------------------------------------------
extern "C" void kernel_launch(void* const* d_in, const int* in_sizes, int n_in,
                              void* d_out, int out_size, void* d_ws, size_t ws_size,
                              hipStream_t stream) {
    const float2* y2    = (const float2*)d_in[0];
    const float*  W     = (const float*)d_in[1];
    const float*  step  = (const float*)d_in[2];
    const int*    polys = (const int*)d_in[3];
    float*        out   = (float*)d_out;
    float2*       pts   = (float2*)d_ws;     // 64*65536*8B = 32 MB

    dim3 gridA(NPTS / 256, NG);
    poca_kernel<<<gridA, 256, 0, stream>>>(y2, W, step, polys, pts);
    fiter_kernel<<<NPTS * 4 / 256, 256, 0, stream>>>(y2, step, pts, out);
}